// Round 1
// baseline (2690.865 us; speedup 1.0000x reference)
//
#include <hip/hip_runtime.h>
#include <math.h>

#define BATCH  256
#define SEQ    1025
#define NSP    1024
#define DIM    384
#define NHALF  512
#define RMERGE 307      // int(1024 * 0.3)
#define NOUTT  718      // 1 + 512 + (512-307)
#define NTILE  128
#define NDT    4        // 512 / NTILE

#define INVS   0.044194173824159220275  // 1/sqrt(512)

// ---- low-frequency basis helpers (13 freqs: DC + 6 cos/sin pairs) ----
__device__ __forceinline__ void trig_tables(double* ct, double* st_) {
  const int t = threadIdx.x;
  if (t < 32) {
    const double ang = (double)t * (3.14159265358979323846 / 16.0); // 2*pi*t/32
    ct[t]  = cos(ang);
    st_[t] = sin(ang);
  }
}

// unscaled basis values for freqs (0,1),(0,2),(1,0),(2,0),(1,1),(1,-1) cos+sin
__device__ __forceinline__ void basis12(const double* ct, const double* st_, int r, double* u) {
  const int y = r >> 5, x = r & 31;
  const double cx = ct[x], sx = st_[x];
  const double cy = ct[y], sy = st_[y];
  u[0]  = cx;                  u[1]  = sx;                 // (0,1)
  u[2]  = 2.0 * cx * cx - 1.0; u[3]  = 2.0 * sx * cx;      // (0,2)
  u[4]  = cy;                  u[5]  = sy;                 // (1,0)
  u[6]  = 2.0 * cy * cy - 1.0; u[7]  = 2.0 * sy * cy;      // (2,0)
  u[8]  = cx * cy - sx * sy;   u[9]  = sx * cy + cx * sy;  // (1,1)  angle x+y
  u[10] = cy * cx + sy * sx;   u[11] = sy * cx - cy * sx;  // (1,-1) angle y-x
}

// ---- P1a: partial projection coefficients (4 r-chunks for occupancy) ----
__global__ __launch_bounds__(384) void k_coef(const float* __restrict__ tokens,
                                              double* __restrict__ pcoef) {
  const int chunk = blockIdx.x;   // 0..3
  const int b = blockIdx.y;
  const int tid = threadIdx.x;    // = channel d, 0..383
  __shared__ double ct[32], st_[32];
  trig_tables(ct, st_);
  __syncthreads();
  double acc[13];
#pragma unroll
  for (int f = 0; f < 13; ++f) acc[f] = 0.0;
  const float* xp = tokens + ((size_t)b * SEQ + 1) * DIM + tid;
  const int r0 = chunk * 256;
  for (int r = r0; r < r0 + 256; ++r) {
    double u[12];
    basis12(ct, st_, r, u);
    const double x = (double)xp[(size_t)r * DIM];
    const double xs = x * INVS;
    acc[0] += x;
#pragma unroll
    for (int f = 0; f < 12; ++f) acc[f + 1] = fma(xs, u[f], acc[f + 1]);
  }
  acc[0] *= (1.0 / 32.0);
  double* cp = pcoef + (((size_t)chunk * BATCH + b) * 13) * DIM + tid;
#pragma unroll
  for (int f = 0; f < 13; ++f) cp[(size_t)f * DIM] = acc[f];
}

// ---- P1b: deterministic reduce of the 4 chunks ----
__global__ __launch_bounds__(256) void k_coef_red(const double* __restrict__ pcoef,
                                                  double* __restrict__ coef) {
  const size_t N = (size_t)BATCH * 13 * DIM;
  const size_t i = (size_t)blockIdx.x * blockDim.x + threadIdx.x;
  if (i >= N) return;
  coef[i] = ((pcoef[i] + pcoef[N + i]) + pcoef[2 * N + i]) + pcoef[3 * N + i];
}

// ---- P2: energy (mean_d hf^2) + token inverse norms, fused ----
__global__ __launch_bounds__(384) void k_energy(const float* __restrict__ tokens,
                                                const double* __restrict__ coef,
                                                double* __restrict__ energy,
                                                double* __restrict__ rnorm) {
  const int rg = blockIdx.x;   // 64 groups of 16 r
  const int b = blockIdx.y;
  const int tid = threadIdx.x; // channel d
  __shared__ double ct[32], st_[32];
  __shared__ double rede[16][8], redn[16][8];
  trig_tables(ct, st_);
  __syncthreads();
  const double* cp = coef + (size_t)b * 13 * DIM + tid;
  double c[13];
#pragma unroll
  for (int f = 0; f < 13; ++f) c[f] = cp[(size_t)f * DIM];
  const float* xp = tokens + ((size_t)b * SEQ + 1) * DIM + tid;
  const int lane = tid & 63, wv = tid >> 6;
  for (int rr = 0; rr < 16; ++rr) {
    const int r = rg * 16 + rr;
    double u[12];
    basis12(ct, st_, r, u);
    double s12 = 0.0;
#pragma unroll
    for (int f = 0; f < 12; ++f) s12 = fma(c[f + 1], u[f], s12);
    const double lp = fma(s12, INVS, c[0] * (1.0 / 32.0));
    const double x = (double)xp[(size_t)r * DIM];
    const double hf = x - lp;
    double e = hf * hf, n2 = x * x;
#pragma unroll
    for (int o = 32; o > 0; o >>= 1) { e += __shfl_down(e, o); n2 += __shfl_down(n2, o); }
    if (lane == 0) { rede[rr][wv] = e; redn[rr][wv] = n2; }
  }
  __syncthreads();
  if (tid < 16) {
    const int r = rg * 16 + tid;
    double es = 0.0, ns = 0.0;
#pragma unroll
    for (int w = 0; w < 6; ++w) { es += rede[tid][w]; ns += redn[tid][w]; }
    energy[(size_t)b * NSP + r] = es * (1.0 / 384.0);
    double nn = sqrt(ns);
    if (nn < 1e-12) nn = 1e-12;
    rnorm[(size_t)b * NSP + r] = 1.0 / nn;
  }
}

// ---- P3: per-batch phi normalization ----
__global__ __launch_bounds__(256) void k_phi(const double* __restrict__ energy,
                                             double* __restrict__ phi) {
  const int b = blockIdx.x;
  const int tid = threadIdx.x;
  __shared__ double smn[4], smx[4];
  const double* ep = energy + (size_t)b * NSP;
  double mn = 1e300, mx = -1e300;
  for (int i = tid; i < NSP; i += 256) {
    const double e = ep[i];
    mn = fmin(mn, e); mx = fmax(mx, e);
  }
#pragma unroll
  for (int o = 32; o > 0; o >>= 1) {
    mn = fmin(mn, __shfl_down(mn, o));
    mx = fmax(mx, __shfl_down(mx, o));
  }
  const int lane = tid & 63, wv = tid >> 6;
  if (lane == 0) { smn[wv] = mn; smx[wv] = mx; }
  __syncthreads();
  mn = fmin(fmin(smn[0], smn[1]), fmin(smn[2], smn[3]));
  mx = fmax(fmax(smx[0], smx[1]), fmax(smx[2], smx[3]));
  const double inv = 1.0 / (mx - mn + 1e-6);
  double* pp = phi + (size_t)b * NSP;
  for (int i = tid; i < NSP; i += 256) pp[i] = (ep[i] - mn) * inv;
}

// ---- Scores: fp64 128x128 tile, 8x8 per thread, fused factor + row argmax ----
__global__ __launch_bounds__(256, 2) void k_scores(const float* __restrict__ tokens,
                                                   const double* __restrict__ phi,
                                                   const double* __restrict__ rnorm,
                                                   double* __restrict__ pmax,
                                                   int* __restrict__ pidx) {
  const int dt = blockIdx.x, st = blockIdx.y, b = blockIdx.z;
  __shared__ double As[NTILE][17];
  __shared__ double Bs[NTILE][17];
  const int tid = threadIdx.x;
  const int tx = tid & 15, ty = tid >> 4;
  double acc[8][8];
#pragma unroll
  for (int i = 0; i < 8; ++i)
#pragma unroll
    for (int j = 0; j < 8; ++j) acc[i][j] = 0.0;

  const float* spat = tokens + (size_t)b * SEQ * DIM + DIM; // spatial token 0
  for (int k0 = 0; k0 < DIM; k0 += 16) {
#pragma unroll
    for (int v = 0; v < 2; ++v) {
      const int idx = tid * 2 + v;
      const int row = idx >> 2, kq = (idx & 3) * 4;
      const float4 av = *(const float4*)(spat + ((size_t)(2 * (st * NTILE + row) + 1)) * DIM + k0 + kq);
      const float4 bv = *(const float4*)(spat + ((size_t)(2 * (dt * NTILE + row))) * DIM + k0 + kq);
      As[row][kq] = av.x; As[row][kq + 1] = av.y; As[row][kq + 2] = av.z; As[row][kq + 3] = av.w;
      Bs[row][kq] = bv.x; Bs[row][kq + 1] = bv.y; Bs[row][kq + 2] = bv.z; Bs[row][kq + 3] = bv.w;
    }
    __syncthreads();
#pragma unroll
    for (int kk = 0; kk < 16; ++kk) {
      double a[8], bb[8];
#pragma unroll
      for (int i = 0; i < 8; ++i) a[i] = As[ty + 16 * i][kk];
#pragma unroll
      for (int j = 0; j < 8; ++j) bb[j] = Bs[tx + 16 * j][kk];
#pragma unroll
      for (int i = 0; i < 8; ++i)
#pragma unroll
        for (int j = 0; j < 8; ++j) acc[i][j] = fma(a[i], bb[j], acc[i][j]);
    }
    __syncthreads();
  }

  const double* phib = phi + (size_t)b * NSP;
  const double* rnb = rnorm + (size_t)b * NSP;
  double rs[8], ps[8], rd[8], pd[8];
#pragma unroll
  for (int i = 0; i < 8; ++i) {
    const int sg = st * NTILE + ty + 16 * i;
    rs[i] = rnb[2 * sg + 1]; ps[i] = phib[2 * sg + 1];
  }
#pragma unroll
  for (int j = 0; j < 8; ++j) {
    const int dg = dt * NTILE + tx + 16 * j;
    rd[j] = rnb[2 * dg]; pd[j] = phib[2 * dg];
  }

  double (*rv)[17] = As;                                   // reuse LDS
  int (*ri)[17] = reinterpret_cast<int (*)[17]>((void*)Bs);
#pragma unroll
  for (int i = 0; i < 8; ++i) {
    double best = -1e300; int bi = 0x7fffffff;
#pragma unroll
    for (int j = 0; j < 8; ++j) {
      const int dg = dt * NTILE + tx + 16 * j;
      const double pm = ps[i] > pd[j] ? ps[i] : pd[j];
      const double sc = acc[i][j] * rs[i] * rd[j] * (1.0 - 0.7 * pm);
      if (sc > best || (sc == best && dg < bi)) { best = sc; bi = dg; }
    }
    rv[ty + 16 * i][tx] = best;
    ri[ty + 16 * i][tx] = bi;
  }
  __syncthreads();
  if (tid < NTILE) {
    double best = -1e300; int bi = 0x7fffffff;
#pragma unroll
    for (int t = 0; t < 16; ++t) {
      const double v = rv[tid][t]; const int id = ri[tid][t];
      if (v > best || (v == best && id < bi)) { best = v; bi = id; }
    }
    const size_t o = ((size_t)b * NHALF + st * NTILE + tid) * NDT + dt;
    pmax[o] = best; pidx[o] = bi;
  }
}

// ---- Select: node argmax across tiles + stable top-307 via rank + keep prefix ----
__global__ __launch_bounds__(512) void k_select(const double* __restrict__ pmax,
                                                const int* __restrict__ pidx,
                                                int* __restrict__ node_idx,
                                                int* __restrict__ sel,
                                                int* __restrict__ keep_pos) {
  const int b = blockIdx.x;
  const int s = threadIdx.x; // 0..511
  __shared__ double nm[512];
  __shared__ int sl[512];
  double best = -1e300; int bi = 0x7fffffff;
  const double* pm = pmax + ((size_t)b * NHALF + s) * NDT;
  const int* pi = pidx + ((size_t)b * NHALF + s) * NDT;
#pragma unroll
  for (int t = 0; t < NDT; ++t) {
    const double v = pm[t]; const int id = pi[t];
    if (v > best || (v == best && id < bi)) { best = v; bi = id; }
  }
  nm[s] = best;
  node_idx[b * NHALF + s] = bi;
  __syncthreads();
  int rank = 0;
  for (int j = 0; j < NHALF; ++j) {
    const double vj = nm[j];
    rank += (vj > best) || (vj == best && j < s);
  }
  const int se = (rank < RMERGE) ? 1 : 0;
  sl[s] = se;
  sel[b * NHALF + s] = se;
  __syncthreads();
  int pos = 0;
  for (int j = 0; j < s; ++j) pos += (sl[j] == 0);
  keep_pos[b * NHALF + s] = pos;
}

// ---- Output assembly: cls + dst copies + unmerged compaction ----
__global__ __launch_bounds__(128) void k_out_init(const float* __restrict__ tokens,
                                                  const int* __restrict__ sel,
                                                  const int* __restrict__ keep_pos,
                                                  float* __restrict__ out) {
  const int t = blockIdx.x;  // 0..1024
  const int b = blockIdx.y;
  const float* sp; float* dp;
  if (t == 0) {
    sp = tokens + (size_t)b * SEQ * DIM;
    dp = out + (size_t)b * NOUTT * DIM;
  } else if (t <= 512) {
    sp = tokens + ((size_t)b * SEQ + (2 * t - 1)) * DIM;      // dst token (spatial 2(t-1))
    dp = out + ((size_t)b * NOUTT + t) * DIM;
  } else {
    const int s = t - 513;
    if (sel[b * NHALF + s]) return;
    sp = tokens + ((size_t)b * SEQ + 2 + 2 * s) * DIM;        // src token (spatial 2s+1)
    dp = out + ((size_t)b * NOUTT + 513 + keep_pos[b * NHALF + s]) * DIM;
  }
  for (int d = threadIdx.x; d < DIM; d += 128) dp[d] = sp[d];
}

// ---- Scatter-merge selected src into dst region of out ----
__global__ __launch_bounds__(128) void k_merge(const float* __restrict__ tokens,
                                               const int* __restrict__ sel,
                                               const int* __restrict__ node_idx,
                                               float* __restrict__ out,
                                               int* __restrict__ cnt) {
  const int s = blockIdx.x, b = blockIdx.y;
  if (!sel[b * NHALF + s]) return;
  const int di = node_idx[b * NHALF + s];
  const float* sp = tokens + ((size_t)b * SEQ + 2 + 2 * s) * DIM;
  float* dp = out + ((size_t)b * NOUTT + 1 + di) * DIM;
  for (int d = threadIdx.x; d < DIM; d += 128) atomicAdd(&dp[d], sp[d]);
  if (threadIdx.x == 0) atomicAdd(&cnt[b * NHALF + di], 1);
}

// ---- Divide merged dst rows by count ----
__global__ __launch_bounds__(128) void k_div(float* __restrict__ out,
                                             const int* __restrict__ cnt) {
  const int t = blockIdx.x, b = blockIdx.y;
  const int c = cnt[b * NHALF + t] + 1;
  if (c == 1) return;
  const float invc = 1.0f / (float)c;
  float* dp = out + ((size_t)b * NOUTT + 1 + t) * DIM;
  for (int d = threadIdx.x; d < DIM; d += 128) dp[d] *= invc;
}

extern "C" void kernel_launch(void* const* d_in, const int* in_sizes, int n_in,
                              void* d_out, int out_size, void* d_ws, size_t ws_size,
                              hipStream_t stream) {
  (void)in_sizes; (void)n_in; (void)out_size; (void)ws_size;
  const float* tokens = (const float*)d_in[0];
  float* out = (float*)d_out;

  char* ws = (char*)d_ws;
  size_t off = 0;
  auto alloc = [&](size_t bytes) -> void* {
    void* p = ws + off;
    off += (bytes + 255) & ~(size_t)255;
    return p;
  };
  double* pcoef   = (double*)alloc((size_t)4 * BATCH * 13 * DIM * 8);
  double* coef    = (double*)alloc((size_t)BATCH * 13 * DIM * 8);
  double* energy  = (double*)alloc((size_t)BATCH * NSP * 8);
  double* rnorm   = (double*)alloc((size_t)BATCH * NSP * 8);
  double* phi     = (double*)alloc((size_t)BATCH * NSP * 8);
  double* pmax    = (double*)alloc((size_t)BATCH * NHALF * NDT * 8);
  int*    pidx    = (int*)alloc((size_t)BATCH * NHALF * NDT * 4);
  int*    node_i  = (int*)alloc((size_t)BATCH * NHALF * 4);
  int*    sel     = (int*)alloc((size_t)BATCH * NHALF * 4);
  int*    keep_p  = (int*)alloc((size_t)BATCH * NHALF * 4);
  int*    cnt     = (int*)alloc((size_t)BATCH * NHALF * 4);

  hipMemsetAsync(cnt, 0, (size_t)BATCH * NHALF * 4, stream);

  k_coef<<<dim3(4, BATCH), 384, 0, stream>>>(tokens, pcoef);
  {
    const size_t N = (size_t)BATCH * 13 * DIM;
    k_coef_red<<<(unsigned)((N + 255) / 256), 256, 0, stream>>>(pcoef, coef);
  }
  k_energy<<<dim3(64, BATCH), 384, 0, stream>>>(tokens, coef, energy, rnorm);
  k_phi<<<BATCH, 256, 0, stream>>>(energy, phi);
  k_scores<<<dim3(NDT, NDT, BATCH), 256, 0, stream>>>(tokens, phi, rnorm, pmax, pidx);
  k_select<<<BATCH, 512, 0, stream>>>(pmax, pidx, node_i, sel, keep_p);
  k_out_init<<<dim3(1025, BATCH), 128, 0, stream>>>(tokens, sel, keep_p, out);
  k_merge<<<dim3(NHALF, BATCH), 128, 0, stream>>>(tokens, sel, node_i, out, cnt);
  k_div<<<dim3(NHALF, BATCH), 128, 0, stream>>>(out, cnt);
}

// Round 2
// 2139.576 us; speedup vs baseline: 1.2577x; 1.2577x over previous
//
#include <hip/hip_runtime.h>
#include <math.h>

#define BATCH  256
#define SEQ    1025
#define NSP    1024
#define DIM    384
#define NHALF  512
#define RMERGE 307      // int(1024 * 0.3)
#define NOUTT  718      // 1 + 512 + (512-307)
#define NTILE  128
#define NDT    4        // 512 / NTILE
#define NCAND  3        // top-3 tracked per (row, tile)
#define EPSM   1e-4f    // fp32 screening margin for fp64 recheck

#define INVS   0.044194173824159220275  // 1/sqrt(512)

// ---- low-frequency basis helpers (13 freqs: DC + 6 cos/sin pairs) ----
__device__ __forceinline__ void trig_tables(double* ct, double* st_) {
  const int t = threadIdx.x;
  if (t < 32) {
    const double ang = (double)t * (3.14159265358979323846 / 16.0); // 2*pi*t/32
    ct[t]  = cos(ang);
    st_[t] = sin(ang);
  }
}

__device__ __forceinline__ void basis12(const double* ct, const double* st_, int r, double* u) {
  const int y = r >> 5, x = r & 31;
  const double cx = ct[x], sx = st_[x];
  const double cy = ct[y], sy = st_[y];
  u[0]  = cx;                  u[1]  = sx;
  u[2]  = 2.0 * cx * cx - 1.0; u[3]  = 2.0 * sx * cx;
  u[4]  = cy;                  u[5]  = sy;
  u[6]  = 2.0 * cy * cy - 1.0; u[7]  = 2.0 * sy * cy;
  u[8]  = cx * cy - sx * sy;   u[9]  = sx * cy + cx * sy;
  u[10] = cy * cx + sy * sx;   u[11] = sy * cx - cy * sx;
}

// ---- P1a: partial projection coefficients ----
__global__ __launch_bounds__(384) void k_coef(const float* __restrict__ tokens,
                                              double* __restrict__ pcoef) {
  const int chunk = blockIdx.x;
  const int b = blockIdx.y;
  const int tid = threadIdx.x;
  __shared__ double ct[32], st_[32];
  trig_tables(ct, st_);
  __syncthreads();
  double acc[13];
#pragma unroll
  for (int f = 0; f < 13; ++f) acc[f] = 0.0;
  const float* xp = tokens + ((size_t)b * SEQ + 1) * DIM + tid;
  const int r0 = chunk * 256;
  for (int r = r0; r < r0 + 256; ++r) {
    double u[12];
    basis12(ct, st_, r, u);
    const double x = (double)xp[(size_t)r * DIM];
    const double xs = x * INVS;
    acc[0] += x;
#pragma unroll
    for (int f = 0; f < 12; ++f) acc[f + 1] = fma(xs, u[f], acc[f + 1]);
  }
  acc[0] *= (1.0 / 32.0);
  double* cp = pcoef + (((size_t)chunk * BATCH + b) * 13) * DIM + tid;
#pragma unroll
  for (int f = 0; f < 13; ++f) cp[(size_t)f * DIM] = acc[f];
}

__global__ __launch_bounds__(256) void k_coef_red(const double* __restrict__ pcoef,
                                                  double* __restrict__ coef) {
  const size_t N = (size_t)BATCH * 13 * DIM;
  const size_t i = (size_t)blockIdx.x * blockDim.x + threadIdx.x;
  if (i >= N) return;
  coef[i] = ((pcoef[i] + pcoef[N + i]) + pcoef[2 * N + i]) + pcoef[3 * N + i];
}

// ---- P2: energy + inverse norms (fp64 + fp32 mirror) ----
__global__ __launch_bounds__(384) void k_energy(const float* __restrict__ tokens,
                                                const double* __restrict__ coef,
                                                double* __restrict__ energy,
                                                double* __restrict__ rnorm,
                                                float* __restrict__ rnf) {
  const int rg = blockIdx.x;
  const int b = blockIdx.y;
  const int tid = threadIdx.x;
  __shared__ double ct[32], st_[32];
  __shared__ double rede[16][8], redn[16][8];
  trig_tables(ct, st_);
  __syncthreads();
  const double* cp = coef + (size_t)b * 13 * DIM + tid;
  double c[13];
#pragma unroll
  for (int f = 0; f < 13; ++f) c[f] = cp[(size_t)f * DIM];
  const float* xp = tokens + ((size_t)b * SEQ + 1) * DIM + tid;
  const int lane = tid & 63, wv = tid >> 6;
  for (int rr = 0; rr < 16; ++rr) {
    const int r = rg * 16 + rr;
    double u[12];
    basis12(ct, st_, r, u);
    double s12 = 0.0;
#pragma unroll
    for (int f = 0; f < 12; ++f) s12 = fma(c[f + 1], u[f], s12);
    const double lp = fma(s12, INVS, c[0] * (1.0 / 32.0));
    const double x = (double)xp[(size_t)r * DIM];
    const double hf = x - lp;
    double e = hf * hf, n2 = x * x;
#pragma unroll
    for (int o = 32; o > 0; o >>= 1) { e += __shfl_down(e, o); n2 += __shfl_down(n2, o); }
    if (lane == 0) { rede[rr][wv] = e; redn[rr][wv] = n2; }
  }
  __syncthreads();
  if (tid < 16) {
    const int r = rg * 16 + tid;
    double es = 0.0, ns = 0.0;
#pragma unroll
    for (int w = 0; w < 6; ++w) { es += rede[tid][w]; ns += redn[tid][w]; }
    energy[(size_t)b * NSP + r] = es * (1.0 / 384.0);
    double nn = sqrt(ns);
    if (nn < 1e-12) nn = 1e-12;
    const double rv = 1.0 / nn;
    rnorm[(size_t)b * NSP + r] = rv;
    rnf[(size_t)b * NSP + r] = (float)rv;
  }
}

// ---- P3: phi normalization (fp64 + fp32 mirror) ----
__global__ __launch_bounds__(256) void k_phi(const double* __restrict__ energy,
                                             double* __restrict__ phi,
                                             float* __restrict__ phif) {
  const int b = blockIdx.x;
  const int tid = threadIdx.x;
  __shared__ double smn[4], smx[4];
  const double* ep = energy + (size_t)b * NSP;
  double mn = 1e300, mx = -1e300;
  for (int i = tid; i < NSP; i += 256) {
    const double e = ep[i];
    mn = fmin(mn, e); mx = fmax(mx, e);
  }
#pragma unroll
  for (int o = 32; o > 0; o >>= 1) {
    mn = fmin(mn, __shfl_down(mn, o));
    mx = fmax(mx, __shfl_down(mx, o));
  }
  const int lane = tid & 63, wv = tid >> 6;
  if (lane == 0) { smn[wv] = mn; smx[wv] = mx; }
  __syncthreads();
  mn = fmin(fmin(smn[0], smn[1]), fmin(smn[2], smn[3]));
  mx = fmax(fmax(smx[0], smx[1]), fmax(smx[2], smx[3]));
  const double inv = 1.0 / (mx - mn + 1e-6);
  double* pp = phi + (size_t)b * NSP;
  float* pf = phif + (size_t)b * NSP;
  for (int i = tid; i < NSP; i += 256) {
    const double v = (ep[i] - mn) * inv;
    pp[i] = v; pf[i] = (float)v;
  }
}

// ---- Scores: fp32 128x128 tile GEMM, fused factor + per-row top-3 per tile ----
__global__ __launch_bounds__(256) void k_scores(const float* __restrict__ tokens,
                                                const float* __restrict__ phif,
                                                const float* __restrict__ rnf,
                                                float* __restrict__ pval,
                                                int* __restrict__ pidx) {
  const int dt = blockIdx.x, st = blockIdx.y, b = blockIdx.z;
  __shared__ float As[NTILE][20];   // stride 20 floats: 16B-aligned rows, 2-way bank alias (free)
  __shared__ float Bs[NTILE][20];
  const int tid = threadIdx.x;
  const int tx = tid & 15, ty = tid >> 4;
  float acc[8][8];
#pragma unroll
  for (int i = 0; i < 8; ++i)
#pragma unroll
    for (int j = 0; j < 8; ++j) acc[i][j] = 0.0f;

  const float* spat = tokens + (size_t)b * SEQ * DIM + DIM;
  for (int k0 = 0; k0 < DIM; k0 += 16) {
#pragma unroll
    for (int v = 0; v < 2; ++v) {
      const int idx = tid * 2 + v;
      const int row = idx >> 2, kq = (idx & 3) * 4;
      const float4 av = *(const float4*)(spat + ((size_t)(2 * (st * NTILE + row) + 1)) * DIM + k0 + kq);
      const float4 bv = *(const float4*)(spat + ((size_t)(2 * (dt * NTILE + row))) * DIM + k0 + kq);
      *(float4*)&As[row][kq] = av;
      *(float4*)&Bs[row][kq] = bv;
    }
    __syncthreads();
#pragma unroll
    for (int kk = 0; kk < 16; kk += 4) {
      float4 a4[8], b4[8];
#pragma unroll
      for (int i = 0; i < 8; ++i) a4[i] = *(const float4*)&As[ty + 16 * i][kk];
#pragma unroll
      for (int j = 0; j < 8; ++j) b4[j] = *(const float4*)&Bs[tx + 16 * j][kk];
#pragma unroll
      for (int i = 0; i < 8; ++i)
#pragma unroll
        for (int j = 0; j < 8; ++j) {
          acc[i][j] = fmaf(a4[i].x, b4[j].x, acc[i][j]);
          acc[i][j] = fmaf(a4[i].y, b4[j].y, acc[i][j]);
          acc[i][j] = fmaf(a4[i].z, b4[j].z, acc[i][j]);
          acc[i][j] = fmaf(a4[i].w, b4[j].w, acc[i][j]);
        }
    }
    __syncthreads();
  }

  const float* phib = phif + (size_t)b * NSP;
  const float* rnb = rnf + (size_t)b * NSP;
  float rd[8], pd[8];
  int dg8[8];
#pragma unroll
  for (int j = 0; j < 8; ++j) {
    const int dg = dt * NTILE + tx + 16 * j;
    dg8[j] = dg;
    rd[j] = rnb[2 * dg]; pd[j] = phib[2 * dg];
  }

  // per-row top-3 within tile, reduced across the 16 tx lanes via shfl_xor
#pragma unroll
  for (int i = 0; i < 8; ++i) {
    const int sg = st * NTILE + ty + 16 * i;
    const float rs = rnb[2 * sg + 1], ps = phib[2 * sg + 1];
    float v0 = -1e30f, v1 = -1e30f, v2 = -1e30f;
    int i0 = -1, i1 = -1, i2 = -1;
#pragma unroll
    for (int j = 0; j < 8; ++j) {
      const float pm = ps > pd[j] ? ps : pd[j];
      const float sc = acc[i][j] * rs * rd[j] * (1.0f - 0.7f * pm);
      if (sc > v0)      { v2 = v1; i2 = i1; v1 = v0; i1 = i0; v0 = sc; i0 = dg8[j]; }
      else if (sc > v1) { v2 = v1; i2 = i1; v1 = sc; i1 = dg8[j]; }
      else if (sc > v2) { v2 = sc; i2 = dg8[j]; }
    }
#pragma unroll
    for (int m = 1; m <= 8; m <<= 1) {
      const float w0 = __shfl_xor(v0, m), w1 = __shfl_xor(v1, m), w2 = __shfl_xor(v2, m);
      const int j0 = __shfl_xor(i0, m), j1 = __shfl_xor(i1, m), j2 = __shfl_xor(i2, m);
      if (w0 > v0)      { v2 = v1; i2 = i1; v1 = v0; i1 = i0; v0 = w0; i0 = j0; }
      else if (w0 > v1) { v2 = v1; i2 = i1; v1 = w0; i1 = j0; }
      else if (w0 > v2) { v2 = w0; i2 = j0; }
      if (w1 > v1)      { v2 = v1; i2 = i1; v1 = w1; i1 = j1; }
      else if (w1 > v2) { v2 = w1; i2 = j1; }
      if (w2 > v2)      { v2 = w2; i2 = j2; }
    }
    if (tx == 0) {
      const size_t o = (((size_t)b * NHALF + st * NTILE + ty + 16 * i) * NDT + dt) * NCAND;
      pval[o] = v0; pval[o + 1] = v1; pval[o + 2] = v2;
      pidx[o] = i0; pidx[o + 1] = i1; pidx[o + 2] = i2;
    }
  }
}

// ---- Refine: exact fp64 score of near-max candidates; exact node_max/node_idx ----
__global__ __launch_bounds__(64) void k_refine(const float* __restrict__ tokens,
                                               const float* __restrict__ pval,
                                               const int* __restrict__ pidx,
                                               const double* __restrict__ phi,
                                               const double* __restrict__ rnorm,
                                               double* __restrict__ node_max,
                                               int* __restrict__ node_idx) {
  const int s = blockIdx.x, b = blockIdx.y;
  const int lane = threadIdx.x;
  const size_t base = ((size_t)b * NHALF + s) * NDT * NCAND;
  float pv[NDT * NCAND]; int pi[NDT * NCAND];
#pragma unroll
  for (int c = 0; c < NDT * NCAND; ++c) { pv[c] = pval[base + c]; pi[c] = pidx[base + c]; }
  float m = -1e30f;
#pragma unroll
  for (int c = 0; c < NDT * NCAND; ++c) m = pv[c] > m ? pv[c] : m;
  const float thr = m - EPSM;

  const float* srcp = tokens + ((size_t)b * SEQ + 2 + 2 * s) * DIM;
  double sv[6];
#pragma unroll
  for (int q = 0; q < 6; ++q) sv[q] = (double)srcp[lane + 64 * q];
  const double phs = phi[(size_t)b * NSP + 2 * s + 1];
  const double rns = rnorm[(size_t)b * NSP + 2 * s + 1];

  double best = -1e300; int bi = 0x7fffffff;
#pragma unroll
  for (int c = 0; c < NDT * NCAND; ++c) {
    if (pv[c] < thr) continue;
    const int j = pi[c];
    const float* dstp = tokens + ((size_t)b * SEQ + 1 + 2 * j) * DIM;
    double dot = 0.0;
#pragma unroll
    for (int q = 0; q < 6; ++q) dot = fma(sv[q], (double)dstp[lane + 64 * q], dot);
#pragma unroll
    for (int o = 32; o > 0; o >>= 1) dot += __shfl_down(dot, o);
    dot = __shfl(dot, 0);
    const double pj = phi[(size_t)b * NSP + 2 * j];
    const double pm = phs > pj ? phs : pj;
    const double sc = dot * rns * rnorm[(size_t)b * NSP + 2 * j] * (1.0 - 0.7 * pm);
    if (sc > best || (sc == best && j < bi)) { best = sc; bi = j; }
  }
  if (lane == 0) {
    node_max[(size_t)b * NHALF + s] = best;
    node_idx[(size_t)b * NHALF + s] = bi;
  }
}

// ---- Select: stable top-307 via rank + keep-position prefix ----
__global__ __launch_bounds__(512) void k_select(const double* __restrict__ node_max,
                                                int* __restrict__ sel,
                                                int* __restrict__ keep_pos) {
  const int b = blockIdx.x;
  const int s = threadIdx.x;
  __shared__ double nm[512];
  __shared__ int sl[512];
  const double best = node_max[(size_t)b * NHALF + s];
  nm[s] = best;
  __syncthreads();
  int rank = 0;
  for (int j = 0; j < NHALF; ++j) {
    const double vj = nm[j];
    rank += (vj > best) || (vj == best && j < s);
  }
  const int se = (rank < RMERGE) ? 1 : 0;
  sl[s] = se;
  sel[b * NHALF + s] = se;
  __syncthreads();
  int pos = 0;
  for (int j = 0; j < s; ++j) pos += (sl[j] == 0);
  keep_pos[b * NHALF + s] = pos;
}

// ---- Output assembly ----
__global__ __launch_bounds__(128) void k_out_init(const float* __restrict__ tokens,
                                                  const int* __restrict__ sel,
                                                  const int* __restrict__ keep_pos,
                                                  float* __restrict__ out) {
  const int t = blockIdx.x;
  const int b = blockIdx.y;
  const float* sp; float* dp;
  if (t == 0) {
    sp = tokens + (size_t)b * SEQ * DIM;
    dp = out + (size_t)b * NOUTT * DIM;
  } else if (t <= 512) {
    sp = tokens + ((size_t)b * SEQ + (2 * t - 1)) * DIM;
    dp = out + ((size_t)b * NOUTT + t) * DIM;
  } else {
    const int s = t - 513;
    if (sel[b * NHALF + s]) return;
    sp = tokens + ((size_t)b * SEQ + 2 + 2 * s) * DIM;
    dp = out + ((size_t)b * NOUTT + 513 + keep_pos[b * NHALF + s]) * DIM;
  }
  const int tid = threadIdx.x;
  if (tid < 96) ((float4*)dp)[tid] = ((const float4*)sp)[tid];
}

__global__ __launch_bounds__(128) void k_merge(const float* __restrict__ tokens,
                                               const int* __restrict__ sel,
                                               const int* __restrict__ node_idx,
                                               float* __restrict__ out,
                                               int* __restrict__ cnt) {
  const int s = blockIdx.x, b = blockIdx.y;
  if (!sel[b * NHALF + s]) return;
  const int di = node_idx[b * NHALF + s];
  const float* sp = tokens + ((size_t)b * SEQ + 2 + 2 * s) * DIM;
  float* dp = out + ((size_t)b * NOUTT + 1 + di) * DIM;
  for (int d = threadIdx.x; d < DIM; d += 128) atomicAdd(&dp[d], sp[d]);
  if (threadIdx.x == 0) atomicAdd(&cnt[b * NHALF + di], 1);
}

__global__ __launch_bounds__(128) void k_div(float* __restrict__ out,
                                             const int* __restrict__ cnt) {
  const int t = blockIdx.x, b = blockIdx.y;
  const int c = cnt[b * NHALF + t] + 1;
  if (c == 1) return;
  const float invc = 1.0f / (float)c;
  float* dp = out + ((size_t)b * NOUTT + 1 + t) * DIM;
  for (int d = threadIdx.x; d < DIM; d += 128) dp[d] *= invc;
}

extern "C" void kernel_launch(void* const* d_in, const int* in_sizes, int n_in,
                              void* d_out, int out_size, void* d_ws, size_t ws_size,
                              hipStream_t stream) {
  (void)in_sizes; (void)n_in; (void)out_size; (void)ws_size;
  const float* tokens = (const float*)d_in[0];
  float* out = (float*)d_out;

  char* ws = (char*)d_ws;
  size_t off = 0;
  auto alloc = [&](size_t bytes) -> void* {
    void* p = ws + off;
    off += (bytes + 255) & ~(size_t)255;
    return p;
  };
  double* pcoef   = (double*)alloc((size_t)4 * BATCH * 13 * DIM * 8);
  double* coef    = (double*)alloc((size_t)BATCH * 13 * DIM * 8);
  double* energy  = (double*)alloc((size_t)BATCH * NSP * 8);
  double* rnorm   = (double*)alloc((size_t)BATCH * NSP * 8);
  double* phi     = (double*)alloc((size_t)BATCH * NSP * 8);
  float*  rnf     = (float*)alloc((size_t)BATCH * NSP * 4);
  float*  phif    = (float*)alloc((size_t)BATCH * NSP * 4);
  float*  pval    = (float*)alloc((size_t)BATCH * NHALF * NDT * NCAND * 4);
  int*    pidx    = (int*)alloc((size_t)BATCH * NHALF * NDT * NCAND * 4);
  double* node_m  = (double*)alloc((size_t)BATCH * NHALF * 8);
  int*    node_i  = (int*)alloc((size_t)BATCH * NHALF * 4);
  int*    sel     = (int*)alloc((size_t)BATCH * NHALF * 4);
  int*    keep_p  = (int*)alloc((size_t)BATCH * NHALF * 4);
  int*    cnt     = (int*)alloc((size_t)BATCH * NHALF * 4);

  hipMemsetAsync(cnt, 0, (size_t)BATCH * NHALF * 4, stream);

  k_coef<<<dim3(4, BATCH), 384, 0, stream>>>(tokens, pcoef);
  {
    const size_t N = (size_t)BATCH * 13 * DIM;
    k_coef_red<<<(unsigned)((N + 255) / 256), 256, 0, stream>>>(pcoef, coef);
  }
  k_energy<<<dim3(64, BATCH), 384, 0, stream>>>(tokens, coef, energy, rnorm, rnf);
  k_phi<<<BATCH, 256, 0, stream>>>(energy, phi, phif);
  k_scores<<<dim3(NDT, NDT, BATCH), 256, 0, stream>>>(tokens, phif, rnf, pval, pidx);
  k_refine<<<dim3(NHALF, BATCH), 64, 0, stream>>>(tokens, pval, pidx, phi, rnorm, node_m, node_i);
  k_select<<<BATCH, 512, 0, stream>>>(node_m, sel, keep_p);
  k_out_init<<<dim3(1025, BATCH), 128, 0, stream>>>(tokens, sel, keep_p, out);
  k_merge<<<dim3(NHALF, BATCH), 128, 0, stream>>>(tokens, sel, node_i, out, cnt);
  k_div<<<dim3(NHALF, BATCH), 128, 0, stream>>>(out, cnt);
}